// Round 1
// baseline (469.381 us; speedup 1.0000x reference)
//
#include <hip/hip_runtime.h>
#include <stdint.h>

#define N_NODES 150000
#define F_IN    500
#define H1      200
#define C1      224      // padded H1 width (14 x 16)  == GEMM2 K pad
#define J2      64       // M * H2
#define K2      224
#define BM      128      // nodes per block
#define NTHREADS 512

#define WS0_ELEMS 114688   // 16 * 224 * 32  (W1^T, tiled per K-step)
#define WS1_ELEMS 14336    // 64 * 224       (masked W2^T, i.e. B2^T)

typedef short short8 __attribute__((ext_vector_type(8)));
typedef float float4v __attribute__((ext_vector_type(4)));

__device__ __forceinline__ short f2bf(float f) {
    uint32_t u = __float_as_uint(f);
    u = (u + 0x7FFFu + ((u >> 16) & 1u)) >> 16;   // RNE
    return (short)u;
}
__device__ __forceinline__ float bf2f(short s) {
    return __uint_as_float(((uint32_t)(uint16_t)s) << 16);
}

// ---------------- prep: build bf16 W1^T (tiled) and masked B2^T in ws ----------------
__global__ __launch_bounds__(256) void prep_kernel(
    const float* __restrict__ W1, const float* __restrict__ W2,
    const float* __restrict__ mask1, short* __restrict__ ws)
{
    int idx = blockIdx.x * 256 + threadIdx.x;
    if (idx < WS0_ELEMS) {
        // ws0[ks][c][kk] = W1[ks*32+kk][c]  (zero-padded c>=200, k>=500)
        int ks = idx / 7168;
        int r  = idx - ks * 7168;
        int c  = r >> 5;
        int k  = ks * 32 + (r & 31);
        float v = (c < H1 && k < F_IN) ? W1[k * H1 + c] : 0.f;
        ws[idx] = f2bf(v);
    } else if (idx < WS0_ELEMS + WS1_ELEMS) {
        // ws1[j][k] = (mask1[m][k]>0) * W2[k][c],  j = m*8+c
        int r = idx - WS0_ELEMS;
        int j = r / K2;
        int k = r - j * K2;
        int m = j >> 3, c = j & 7;
        float v = 0.f;
        if (k < H1 && mask1[m * H1 + k] > 0.f) v = W2[k * 8 + c];
        ws[idx] = f2bf(v);
    }
}

// ---------------- fused main kernel ----------------
// LDS map (81920 B total = 80 KiB -> 2 blocks/CU):
//   region1 [0, 22528):  phase1: as[128][32] bf16 (swz) @0, bt[224][32] bf16 (swz) @8192
//                        phase2: zs[128][72] bf16 @0, smalls (944 f32) @18432
//   h1s [22528, 81920):  [128][232] bf16
__global__ __launch_bounds__(NTHREADS, 4) void fused_kernel(
    const float* __restrict__ x,  const float* __restrict__ b1,
    const float* __restrict__ b2, const float* __restrict__ mask2,
    const float* __restrict__ hw1, const float* __restrict__ hb1,
    const float* __restrict__ hw2, const float* __restrict__ hb2,
    const short* __restrict__ ws, float* __restrict__ out)
{
    __shared__ __align__(16) char lds[81920];
    short* as  = (short*)lds;                 // [128][32], 16B-unit XOR swizzle
    short* bt  = (short*)(lds + 8192);        // [224][32], 16B-unit XOR swizzle
    short* zs  = (short*)lds;                 // [128][72] (overlay, phase2)
    float* smalls = (float*)(lds + 18432);    // 944 floats (phase2)
    short* h1s = (short*)(lds + 22528);       // [128][232]

    const int tid  = threadIdx.x;
    const int lane = tid & 63;
    const int wid  = tid >> 6;
    const int l15  = lane & 15;
    const int l4   = lane >> 4;
    const int n0   = blockIdx.x * BM;

    const int wrow = wid >> 1;   // 0..3  (32 rows each)
    const int wcol = wid & 1;    // 0..1  (7 col-frags each in GEMM1, 2 in GEMM2)

    // ---- GEMM1: h1[128][224] = x_tile[128][512] @ W1pad[512][224] ----
    float4v acc[2][7];
    #pragma unroll
    for (int i = 0; i < 2; ++i)
        #pragma unroll
        for (int j = 0; j < 7; ++j) acc[i][j] = (float4v)0.f;

    // staging mapping for A: thread -> (row, 16B unit)
    const int srow = tid >> 2;          // 0..127
    const int su   = tid & 3;           // 0..3
    const long grow = (long)(n0 + srow) * F_IN;
    const bool rowok = (n0 + srow) < N_NODES;
    short* aswr = as + srow * 32 + ((su ^ ((srow >> 1) & 3)) * 8);

    // fragment read addresses (constant over K-loop)
    const short* afrag[2];
    #pragma unroll
    for (int i = 0; i < 2; ++i) {
        int row = wrow * 32 + i * 16 + l15;
        afrag[i] = as + row * 32 + ((l4 ^ ((row >> 1) & 3)) * 8);
    }
    const short* bfrag[7];
    #pragma unroll
    for (int j = 0; j < 7; ++j) {
        int col = (wcol * 7 + j) * 16 + l15;
        bfrag[j] = bt + col * 32 + ((l4 ^ ((col >> 1) & 3)) * 8);
    }

    for (int ks = 0; ks < 16; ++ks) {
        __syncthreads();
        // stage A: x fp32 -> bf16, 8 elems/thread
        {
            int k0 = ks * 32 + su * 8;
            float xv[8];
            if (rowok && (k0 + 7) < F_IN) {
                const float4* p = (const float4*)(x + grow + k0);
                float4 a = p[0], b = p[1];
                xv[0]=a.x; xv[1]=a.y; xv[2]=a.z; xv[3]=a.w;
                xv[4]=b.x; xv[5]=b.y; xv[6]=b.z; xv[7]=b.w;
            } else {
                #pragma unroll
                for (int e = 0; e < 8; ++e)
                    xv[e] = (rowok && (k0 + e) < F_IN) ? x[grow + k0 + e] : 0.f;
            }
            short8 sv;
            #pragma unroll
            for (int e = 0; e < 8; ++e) sv[e] = f2bf(xv[e]);
            *(short8*)aswr = sv;
        }
        // stage B: W1^T tile (contiguous in ws), 896 16B-units
        {
            const short* src = ws + ks * 7168;
            int uu = tid;
            {
                int c = uu >> 2, u = uu & 3;
                short8 w = *(const short8*)(src + uu * 8);
                *(short8*)(bt + c * 32 + ((u ^ ((c >> 1) & 3)) * 8)) = w;
            }
            uu = tid + NTHREADS;
            if (uu < 896) {
                int c = uu >> 2, u = uu & 3;
                short8 w = *(const short8*)(src + uu * 8);
                *(short8*)(bt + c * 32 + ((u ^ ((c >> 1) & 3)) * 8)) = w;
            }
        }
        __syncthreads();
        short8 a0 = *(const short8*)afrag[0];
        short8 a1 = *(const short8*)afrag[1];
        #pragma unroll
        for (int j = 0; j < 7; ++j) {
            short8 b = *(const short8*)bfrag[j];
            acc[0][j] = __builtin_amdgcn_mfma_f32_16x16x32_bf16(a0, b, acc[0][j], 0, 0, 0);
            acc[1][j] = __builtin_amdgcn_mfma_f32_16x16x32_bf16(a1, b, acc[1][j], 0, 0, 0);
        }
    }
    __syncthreads();   // region1 (as/bt) now dead

    // stage small parameter arrays into region1 tail
    for (int i = tid; i < 944; i += NTHREADS) {
        float v;
        if      (i < 224) v = (i < H1) ? b1[i] : 0.f;            // b1s @0
        else if (i < 232) v = b2[i - 224];                        // b2s @224
        else if (i < 296) v = (mask2[i - 232] > 0.f) ? 1.f : 0.f; // m2s @232
        else if (i < 808) v = hw1[i - 296];                       // hw1s @296
        else if (i < 872) v = hb1[i - 808];                       // hb1s @808
        else if (i < 936) v = hw2[i - 872];                       // hw2s @872
        else              v = hb2[i - 936];                       // hb2s @936
        smalls[i] = v;
    }
    __syncthreads();

    // GEMM1 epilogue: bias + relu -> h1s (bf16)
    #pragma unroll
    for (int j = 0; j < 7; ++j) {
        int col = (wcol * 7 + j) * 16 + l15;
        float bb = smalls[col];
        #pragma unroll
        for (int i = 0; i < 2; ++i) {
            int rowb = wrow * 32 + i * 16 + l4 * 4;
            #pragma unroll
            for (int r = 0; r < 4; ++r) {
                float v = acc[i][j][r] + bb;
                v = v > 0.f ? v : 0.f;
                h1s[(rowb + r) * 232 + col] = f2bf(v);
            }
        }
    }

    // load B2 fragments global->regs (after acc freed; hides L2 latency behind barrier)
    short8 b2f[7][2];
    #pragma unroll
    for (int s = 0; s < 7; ++s)
        #pragma unroll
        for (int jj = 0; jj < 2; ++jj) {
            int j = (wcol * 2 + jj) * 16 + l15;
            b2f[s][jj] = *(const short8*)(ws + WS0_ELEMS + j * K2 + s * 32 + l4 * 8);
        }
    __syncthreads();   // h1s visible

    // ---- GEMM2: h2[128][64] = h1s[128][224] @ B2[224][64] ----
    float4v acc2[2][2];
    #pragma unroll
    for (int i = 0; i < 2; ++i)
        #pragma unroll
        for (int jj = 0; jj < 2; ++jj) acc2[i][jj] = (float4v)0.f;

    #pragma unroll
    for (int s = 0; s < 7; ++s) {
        short8 a2[2];
        #pragma unroll
        for (int i = 0; i < 2; ++i) {
            int row = wrow * 32 + i * 16 + l15;
            a2[i] = *(const short8*)(h1s + row * 232 + s * 32 + l4 * 8);
        }
        #pragma unroll
        for (int i = 0; i < 2; ++i)
            #pragma unroll
            for (int jj = 0; jj < 2; ++jj)
                acc2[i][jj] = __builtin_amdgcn_mfma_f32_16x16x32_bf16(a2[i], b2f[s][jj], acc2[i][jj], 0, 0, 0);
    }

    // GEMM2 epilogue: z = (h2 + b2) * m2 -> zs (bf16)
    #pragma unroll
    for (int jj = 0; jj < 2; ++jj) {
        int j = (wcol * 2 + jj) * 16 + l15;
        int c = j & 7;
        float bias  = smalls[224 + c];
        float scale = smalls[232 + j];
        #pragma unroll
        for (int i = 0; i < 2; ++i) {
            int rowb = wrow * 32 + i * 16 + l4 * 4;
            #pragma unroll
            for (int r = 0; r < 4; ++r) {
                float z = (acc2[i][jj][r] + bias) * scale;
                zs[(rowb + r) * 72 + j] = f2bf(z);
            }
        }
    }
    __syncthreads();

    // ---- head: per (node, module) tiny MLP + sigmoid ----
    {
        int n  = tid >> 2;          // 0..127
        int m0 = (tid & 3) * 2;     // 0,2,4,6 ; thread does modules m0, m0+1
        short8 za = *(const short8*)(zs + n * 72 + m0 * 8);
        short8 zb = *(const short8*)(zs + n * 72 + m0 * 8 + 8);
        float o[2];
        #pragma unroll
        for (int mm = 0; mm < 2; ++mm) {
            int m = m0 + mm;
            float zv[8];
            #pragma unroll
            for (int c = 0; c < 8; ++c) zv[c] = bf2f(mm == 0 ? za[c] : zb[c]);
            float hid[8];
            #pragma unroll
            for (int h = 0; h < 8; ++h) hid[h] = smalls[808 + m * 8 + h];
            #pragma unroll
            for (int c = 0; c < 8; ++c) {
                float zc = zv[c];
                const float* w = smalls + 296 + (m * 8 + c) * 8;
                #pragma unroll
                for (int h = 0; h < 8; ++h) hid[h] += zc * w[h];
            }
            float u = smalls[936 + m];
            #pragma unroll
            for (int h = 0; h < 8; ++h) {
                float hv = hid[h] > 0.f ? hid[h] : 0.f;
                u += hv * smalls[872 + m * 8 + h];
            }
            o[mm] = 1.f / (1.f + __expf(-u));
        }
        int gn = n0 + n;
        if (gn < N_NODES) {
            float2 ov = make_float2(o[0], o[1]);
            *(float2*)(out + (long)gn * 8 + m0) = ov;
        }
    }
}

extern "C" void kernel_launch(void* const* d_in, const int* in_sizes, int n_in,
                              void* d_out, int out_size, void* d_ws, size_t ws_size,
                              hipStream_t stream)
{
    const float* x     = (const float*)d_in[0];
    const float* W1    = (const float*)d_in[1];
    const float* b1    = (const float*)d_in[2];
    const float* W2    = (const float*)d_in[3];
    const float* b2    = (const float*)d_in[4];
    const float* mask1 = (const float*)d_in[5];
    const float* mask2 = (const float*)d_in[6];
    const float* hw1   = (const float*)d_in[7];
    const float* hb1   = (const float*)d_in[8];
    const float* hw2   = (const float*)d_in[9];
    const float* hb2   = (const float*)d_in[10];
    short* ws  = (short*)d_ws;
    float* out = (float*)d_out;

    if (ws_size < (size_t)(WS0_ELEMS + WS1_ELEMS) * sizeof(short)) return;

    int prep_blocks = (WS0_ELEMS + WS1_ELEMS + 255) / 256;
    prep_kernel<<<prep_blocks, 256, 0, stream>>>(W1, W2, mask1, ws);

    int main_blocks = (N_NODES + BM - 1) / BM;
    fused_kernel<<<main_blocks, NTHREADS, 0, stream>>>(
        x, b1, b2, mask2, hw1, hb1, hw2, hb2, ws, out);
}

// Round 6
// 460.441 us; speedup vs baseline: 1.0194x; 1.0194x over previous
//
#include <hip/hip_runtime.h>
#include <stdint.h>

#define NN       150000
#define FF       500
#define XLIM     (NN*FF - 4)       // 74999996, 16B-aligned clamp for x loads
#define NTHREADS 512
#define NSTEPS   16

// ws layout (bf16 elems): ws0 = 16 steps x [256 c][32 k] pre-swizzled W1^T; ws1 = B2^T [64][224]
#define WS0_ELEMS 131072
#define WS1_ELEMS 14336

// LDS map (128 KiB):
//  bufA[2]  @ 0      : 2 x 16384 B   ([128 rows][32 k] f32, 16B-unit swizzle p = u^(r&7))
//  bufB[2]  @ 32768  : 2 x 16384 B   ([256 c][32 k] bf16, swizzle baked into ws)
//  h1s      @ 65536  : 65536 B       ([128][256] bf16, unit swizzle p = u^(r&7))
//  smalls   @ 0      : 944 f32 (overlay on bufA, post-K-loop)
//  zs       @ 4096   : [128][72] bf16 (overlay on bufA, post-K-loop)
#define A_STEP   16384
#define B_BASE   32768
#define H1S_BASE 65536
#define ZS_BASE  4096

typedef short short8 __attribute__((ext_vector_type(8)));
typedef float float4v __attribute__((ext_vector_type(4)));

__device__ __forceinline__ short f2bf(float f) {
    uint32_t u = __float_as_uint(f);
    u = (u + 0x7FFFu + ((u >> 16) & 1u)) >> 16;   // RNE
    return (short)u;
}
__device__ __forceinline__ float bf2f(short s) {
    return __uint_as_float(((uint32_t)(uint16_t)s) << 16);
}

// ---------------- prep: build swizzled bf16 W1^T tiles and masked B2^T in ws ----------------
__global__ __launch_bounds__(256) void prep_kernel(
    const float* __restrict__ W1, const float* __restrict__ W2,
    const float* __restrict__ mask1, short* __restrict__ ws)
{
    int idx = blockIdx.x * 256 + threadIdx.x;
    if (idx < WS0_ELEMS) {
        // step t, row c (=output col), phys 16B-unit p, elem ee.
        // slot holds logical k-unit u = p ^ (c&3):  k = t*32 + u*8 + ee
        int t  = idx >> 13;
        int r  = idx & 8191;
        int c  = r >> 5;
        int e  = r & 31;
        int p  = e >> 3, ee = e & 7;
        int k  = t * 32 + ((p ^ (c & 3)) << 3) + ee;
        float v = (c < 200 && k < 500) ? W1[k * 200 + c] : 0.f;
        ws[idx] = f2bf(v);
    } else if (idx < WS0_ELEMS + WS1_ELEMS) {
        // ws1[j][k] = (mask1[m][k]>0) * W2[k][c],  j = m*8+c
        int r = idx - WS0_ELEMS;
        int j = r / 224;
        int k = r - j * 224;
        int m = j >> 3, c = j & 7;
        float v = 0.f;
        if (k < 200 && mask1[m * 200 + k] > 0.f) v = W2[k * 8 + c];
        ws[idx] = f2bf(v);
    }
}

#define GL16(gp, loff) __builtin_amdgcn_global_load_lds(                         \
    (const __attribute__((address_space(1))) uint32_t*)(gp),                     \
    (__attribute__((address_space(3))) uint32_t*)(lds + (loff)), 16, 0, 0)

__global__ __launch_bounds__(NTHREADS, 2) void fused_kernel(
    const float* __restrict__ x,  const float* __restrict__ b1,
    const float* __restrict__ b2, const float* __restrict__ mask2,
    const float* __restrict__ hw1, const float* __restrict__ hb1,
    const float* __restrict__ hw2, const float* __restrict__ hb2,
    const short* __restrict__ ws, float* __restrict__ out)
{
    __shared__ __align__(16) char lds[131072];
    const int tid  = threadIdx.x;
    const int lane = tid & 63;
    const int w    = tid >> 6;
    const int l15  = lane & 15;
    const int l4   = lane >> 4;
    const int n0   = blockIdx.x * 128;
    const int wrow = w >> 1;     // 0..3
    const int wcol = w & 1;      // 0..1

    // ---- per-lane staging bases ----
    int baseA[2];
    #pragma unroll
    for (int q = 0; q < 2; ++q) {
        int r  = w * 16 + q * 8 + (lane >> 3);     // local row 0..127
        int p  = lane & 7;                         // phys 16B unit (4 f32)
        int rg = n0 + r; if (rg > NN - 1) rg = NN - 1;
        baseA[q] = rg * FF + ((p ^ (r & 7)) << 2); // f32 index of logical unit
    }
    const int dst0 = w * 2048;          // wave-uniform LDS byte base, issue 0
    const int dst1 = w * 2048 + 1024;   // issue 1
    const short* srcB0 = ws + w * 1024 + lane * 8;
    const short* srcB1 = srcB0 + 512;

    // ---- fragment read offsets (byte, within a step buffer) ----
    int offA[2][2], offB[7];
    #pragma unroll
    for (int i = 0; i < 2; ++i) {
        int r = wrow * 32 + i * 16 + l15;
        #pragma unroll
        for (int j = 0; j < 2; ++j) {
            int u = 2 * l4 + j;
            offA[i][j] = r * 128 + ((u ^ (r & 7)) << 4);
        }
    }
    #pragma unroll
    for (int j = 0; j < 7; ++j) {
        int c = wcol * 112 + j * 16 + l15;
        offB[j] = c * 64 + ((l4 ^ (c & 3)) << 4);
    }

    float4v acc[2][7];
    #pragma unroll
    for (int i = 0; i < 2; ++i)
        #pragma unroll
        for (int j = 0; j < 7; ++j) acc[i][j] = (float4v)0.f;

    // ---- K-loop: 2-phase, double-buffered, counted vmcnt ----
    {   // prologue: stage step 0 into buf 0
        int i0 = baseA[0]; if (i0 > XLIM) i0 = XLIM;
        int i1 = baseA[1]; if (i1 > XLIM) i1 = XLIM;
        GL16(x + i0, dst0);
        GL16(x + i1, dst1);
        GL16(srcB0, B_BASE + dst0);
        GL16(srcB1, B_BASE + dst1);
    }
    #pragma unroll
    for (int t = 0; t < NSTEPS; ++t) {
        const int sel = t & 1;
        if (t < NSTEPS - 1) {
            const int o = (sel ^ 1) * A_STEP;
            int i0 = baseA[0] + (t + 1) * 32; if (i0 > XLIM) i0 = XLIM;
            int i1 = baseA[1] + (t + 1) * 32; if (i1 > XLIM) i1 = XLIM;
            GL16(x + i0, o + dst0);
            GL16(x + i1, o + dst1);
            GL16(srcB0 + (t + 1) * 8192, B_BASE + o + dst0);
            GL16(srcB1 + (t + 1) * 8192, B_BASE + o + dst1);
            asm volatile("s_waitcnt vmcnt(4)" ::: "memory");
        } else {
            asm volatile("s_waitcnt vmcnt(0)" ::: "memory");
        }
        __builtin_amdgcn_s_barrier();
        asm volatile("" ::: "memory");

        const char* pa = lds + sel * A_STEP;
        const char* pb = lds + B_BASE + sel * A_STEP;
        float4v a00 = *(const float4v*)(pa + offA[0][0]);
        float4v a01 = *(const float4v*)(pa + offA[0][1]);
        float4v a10 = *(const float4v*)(pa + offA[1][0]);
        float4v a11 = *(const float4v*)(pa + offA[1][1]);
        short8 a0, a1;
        #pragma unroll
        for (int e = 0; e < 4; ++e) { a0[e] = f2bf(a00[e]); a0[4+e] = f2bf(a01[e]); }
        #pragma unroll
        for (int e = 0; e < 4; ++e) { a1[e] = f2bf(a10[e]); a1[4+e] = f2bf(a11[e]); }
        #pragma unroll
        for (int j = 0; j < 7; ++j) {
            short8 b = *(const short8*)(pb + offB[j]);
            acc[0][j] = __builtin_amdgcn_mfma_f32_16x16x32_bf16(a0, b, acc[0][j], 0, 0, 0);
            acc[1][j] = __builtin_amdgcn_mfma_f32_16x16x32_bf16(a1, b, acc[1][j], 0, 0, 0);
        }
        asm volatile("" ::: "memory");
        __builtin_amdgcn_s_barrier();
        asm volatile("" ::: "memory");
    }

    // ---- tail: smalls staging (overlay on bufA) ----
    float* smalls = (float*)lds;
    for (int i = tid; i < 944; i += NTHREADS) {
        float v;
        if      (i < 224) v = (i < 200) ? b1[i] : 0.f;            // b1s @0
        else if (i < 232) v = b2[i - 224];                        // b2s @224
        else if (i < 296) v = (mask2[i - 232] > 0.f) ? 1.f : 0.f; // m2s @232
        else if (i < 808) v = hw1[i - 296];                       // hw1s @296
        else if (i < 872) v = hb1[i - 808];                       // hb1s @808
        else if (i < 936) v = hw2[i - 872];                       // hw2s @872
        else              v = hb2[i - 936];                       // hb2s @936
        smalls[i] = v;
    }
    __syncthreads();

    // ---- GEMM1 epilogue: bias + relu -> h1s (bf16, unit-swizzled, stride 512 B) ----
    #pragma unroll
    for (int j = 0; j < 7; ++j) {
        int col = (wcol * 7 + j) * 16 + l15;
        float bb = smalls[col];
        int u = col >> 3, lo = (col & 7) * 2;
        #pragma unroll
        for (int i = 0; i < 2; ++i) {
            int rowb = wrow * 32 + i * 16 + l4 * 4;
            #pragma unroll
            for (int r = 0; r < 4; ++r) {
                int row = rowb + r;
                float v = acc[i][j][r] + bb;
                v = v > 0.f ? v : 0.f;
                *(short*)(lds + H1S_BASE + row * 512 + ((u ^ (row & 7)) << 4) + lo) = f2bf(v);
            }
        }
    }

    // B2 fragments global->regs (L2-hot ws1)
    short8 b2f[7][2];
    #pragma unroll
    for (int s = 0; s < 7; ++s)
        #pragma unroll
        for (int jj = 0; jj < 2; ++jj) {
            int j = (wcol * 2 + jj) * 16 + l15;
            b2f[s][jj] = *(const short8*)(ws + WS0_ELEMS + j * 224 + s * 32 + l4 * 8);
        }
    __syncthreads();

    // ---- GEMM2: h2[128][64] = h1s[128][224] @ B2[224][64] ----
    float4v acc2[2][2];
    #pragma unroll
    for (int i = 0; i < 2; ++i)
        #pragma unroll
        for (int jj = 0; jj < 2; ++jj) acc2[i][jj] = (float4v)0.f;

    #pragma unroll
    for (int s = 0; s < 7; ++s) {
        short8 a2[2];
        #pragma unroll
        for (int i = 0; i < 2; ++i) {
            int row = wrow * 32 + i * 16 + l15;
            int u = s * 4 + l4;
            a2[i] = *(const short8*)(lds + H1S_BASE + row * 512 + ((u ^ (row & 7)) << 4));
        }
        #pragma unroll
        for (int i = 0; i < 2; ++i)
            #pragma unroll
            for (int jj = 0; jj < 2; ++jj)
                acc2[i][jj] = __builtin_amdgcn_mfma_f32_16x16x32_bf16(a2[i], b2f[s][jj], acc2[i][jj], 0, 0, 0);
    }

    // GEMM2 epilogue: z = (h2 + b2) * m2 -> zs (bf16)
    short* zs = (short*)(lds + ZS_BASE);
    #pragma unroll
    for (int jj = 0; jj < 2; ++jj) {
        int j = (wcol * 2 + jj) * 16 + l15;
        int c = j & 7;
        float bias  = smalls[224 + c];
        float scale = smalls[232 + j];
        #pragma unroll
        for (int i = 0; i < 2; ++i) {
            int rowb = wrow * 32 + i * 16 + l4 * 4;
            #pragma unroll
            for (int r = 0; r < 4; ++r) {
                float z = (acc2[i][jj][r] + bias) * scale;
                zs[(rowb + r) * 72 + j] = f2bf(z);
            }
        }
    }
    __syncthreads();

    // ---- head: per (node, module-pair) tiny MLP + sigmoid ----
    {
        int n  = tid >> 2;          // 0..127
        int m0 = (tid & 3) * 2;     // 0,2,4,6
        short8 za = *(const short8*)(zs + n * 72 + m0 * 8);
        short8 zb = *(const short8*)(zs + n * 72 + m0 * 8 + 8);
        float o[2];
        #pragma unroll
        for (int mm = 0; mm < 2; ++mm) {
            int m = m0 + mm;
            float hid[8];
            #pragma unroll
            for (int h = 0; h < 8; ++h) hid[h] = smalls[808 + m * 8 + h];
            #pragma unroll
            for (int c = 0; c < 8; ++c) {
                float zc = bf2f(mm == 0 ? za[c] : zb[c]);
                const float* wv = smalls + 296 + (m * 8 + c) * 8;
                #pragma unroll
                for (int h = 0; h < 8; ++h) hid[h] += zc * wv[h];
            }
            float u = smalls[936 + m];
            #pragma unroll
            for (int h = 0; h < 8; ++h) {
                float hv = hid[h] > 0.f ? hid[h] : 0.f;
                u += hv * smalls[872 + m * 8 + h];
            }
            o[mm] = 1.f / (1.f + __expf(-u));
        }
        int gn = n0 + n;
        if (gn < NN) {
            float2 ov = make_float2(o[0], o[1]);
            *(float2*)(out + (long)gn * 8 + m0) = ov;
        }
    }
}

extern "C" void kernel_launch(void* const* d_in, const int* in_sizes, int n_in,
                              void* d_out, int out_size, void* d_ws, size_t ws_size,
                              hipStream_t stream)
{
    const float* x     = (const float*)d_in[0];
    const float* W1    = (const float*)d_in[1];
    const float* b1    = (const float*)d_in[2];
    const float* W2    = (const float*)d_in[3];
    const float* b2    = (const float*)d_in[4];
    const float* mask1 = (const float*)d_in[5];
    const float* mask2 = (const float*)d_in[6];
    const float* hw1   = (const float*)d_in[7];
    const float* hb1   = (const float*)d_in[8];
    const float* hw2   = (const float*)d_in[9];
    const float* hb2   = (const float*)d_in[10];
    short* ws  = (short*)d_ws;
    float* out = (float*)d_out;

    if (ws_size < (size_t)(WS0_ELEMS + WS1_ELEMS) * sizeof(short)) return;

    int prep_blocks = (WS0_ELEMS + WS1_ELEMS + 255) / 256;
    prep_kernel<<<prep_blocks, 256, 0, stream>>>(W1, W2, mask1, ws);

    int main_blocks = (NN + 127) / 128;   // 1172
    fused_kernel<<<main_blocks, NTHREADS, 0, stream>>>(
        x, b1, b2, mask2, hw1, hb1, hw2, hb2, ws, out);
}